// Round 12
// baseline (550.612 us; speedup 1.0000x reference)
//
#include <hip/hip_runtime.h>
#include <hip/hip_cooperative_groups.h>
#include <stdint.h>

namespace cg = cooperative_groups;

#define BATCH 2
#define SEQ   1024
#define DIM_  1024
#define DS_   16
#define DI_   2048
#define NTOK  (BATCH*SEQ)   // 2048
#define NSEG  16
#define LSEG  (SEQ/NSEG)    // 64

typedef unsigned short u16;
using s16x8 = __attribute__((ext_vector_type(8))) short;
using f32x4 = __attribute__((ext_vector_type(4))) float;
using u16x4 = __attribute__((ext_vector_type(4))) unsigned short;
using u16x8 = __attribute__((ext_vector_type(8))) unsigned short;

__device__ __forceinline__ float bf2f(u16 u) {
  union { unsigned int i; float f; } c; c.i = ((unsigned int)u) << 16; return c.f;
}
__device__ __forceinline__ u16 f2bf(float f) {
  union { float f; unsigned int i; } c; c.f = f;
  unsigned int r = c.i + 0x7fffu + ((c.i >> 16) & 1u);
  return (u16)(r >> 16);
}
__device__ __forceinline__ float softplus_f(float x) {
  return (x > 15.f) ? x : __logf(1.f + __expf(x));
}
__device__ __forceinline__ u16x4 f4_to_bf(float4 v) {
  u16x4 r; r[0] = f2bf(v.x); r[1] = f2bf(v.y); r[2] = f2bf(v.z); r[3] = f2bf(v.w);
  return r;
}

// ---------------- merged: weight conversions + LayerNorm ----------------
#define N4_INW  (2 * DI_ * DIM_ / 4)   // 1048576
#define N4_OUTW (DIM_ * DI_ / 4)       // 524288
#define CVT_BLOCKS ((N4_INW + N4_OUTW + 32768) / 256)   // 6272
__global__ __launch_bounds__(256) void cvt_ln_kernel(const float* __restrict__ in_w,
    const float* __restrict__ out_w, const float* __restrict__ xproj_w,
    const float* __restrict__ x, const float* __restrict__ nw,
    const float* __restrict__ nb, u16* __restrict__ in_w_bf,
    u16* __restrict__ out_w_bf, u16* __restrict__ xpw_bf, u16* __restrict__ xn) {
  int tid = threadIdx.x;
  if (blockIdx.x < CVT_BLOCKS) {
    int i = blockIdx.x * 256 + tid;
    if (i < N4_INW) {
      ((u16x4*)in_w_bf)[i] = f4_to_bf(((const float4*)in_w)[i]);
    } else if (i < N4_INW + N4_OUTW) {
      int j = i - N4_INW;
      ((u16x4*)out_w_bf)[j] = f4_to_bf(((const float4*)out_w)[j]);
    } else {
      int j = i - (N4_INW + N4_OUTW);
      if (j >= 32768) return;
      int p = (j * 4) >> 11;
      u16x4 r;
      if (p < 33) r = f4_to_bf(((const float4*)xproj_w)[j]);
      else { r[0] = 0; r[1] = 0; r[2] = 0; r[3] = 0; }
      ((u16x4*)xpw_bf)[j] = r;
    }
    return;
  }
  // LayerNorm branch
  int t = blockIdx.x - CVT_BLOCKS;
  const float* row = x + (size_t)t * DIM_;
  float4 v = ((const float4*)row)[tid];
  float f[4] = {v.x, v.y, v.z, v.w};
  float s = 0.f, sq = 0.f;
#pragma unroll
  for (int j = 0; j < 4; j++) { s += f[j]; sq += f[j] * f[j]; }
#pragma unroll
  for (int m = 1; m < 64; m <<= 1) { s += __shfl_xor(s, m); sq += __shfl_xor(sq, m); }
  __shared__ float rs_[4], rq_[4];
  int wv = tid >> 6;
  if ((tid & 63) == 0) { rs_[wv] = s; rq_[wv] = sq; }
  __syncthreads();
  s = rs_[0] + rs_[1] + rs_[2] + rs_[3];
  sq = rq_[0] + rq_[1] + rq_[2] + rq_[3];
  float mu = s * (1.0f / DIM_);
  float var = sq * (1.0f / DIM_) - mu * mu;
  float rstd = rsqrtf(var + 1e-5f);
  float4 wn = ((const float4*)nw)[tid];
  float4 bn = ((const float4*)nb)[tid];
  u16x4 o;
  o[0] = f2bf((f[0] - mu) * rstd * wn.x + bn.x);
  o[1] = f2bf((f[1] - mu) * rstd * wn.y + bn.y);
  o[2] = f2bf((f[2] - mu) * rstd * wn.z + bn.z);
  o[3] = f2bf((f[3] - mu) * rstd * wn.w + bn.w);
  *(u16x4*)(xn + (size_t)t * DIM_ + tid * 4) = o;
}

// ---------------- GEMM C = A(M,K)bf16 * W(N,K)^T bf16, f32 acc ----------------
template<int TBM, int TBN, int BK, typename OUT, int EPI, int KSPLIT = 1, int SWZ = 0>
__global__ __launch_bounds__(256) void gemm_bt(const u16* __restrict__ A,
    const u16* __restrict__ Wt, OUT* __restrict__ C, const float* __restrict__ X,
    int M, int N, int K) {
  constexpr int LDT = BK + 8;
  constexpr int TPR = BK / 8;
  constexpr int RPP = 256 / TPR;
  constexpr int ALn = TBM / RPP;
  constexpr int BLn = TBN / RPP;
  constexpr int KK = BK / 32;
  constexpr int WM = TBM / 2, WN = TBN / 2;
  constexpr int MI = WM / 16, NJ = WN / 16;
  __shared__ __align__(16) u16 sA[TBM * LDT];
  __shared__ __align__(16) u16 sB[TBN * LDT];
  const int tid = threadIdx.x;
  const int lane = tid & 63, wv = tid >> 6;
  const int wm = (wv >> 1) * WM, wn = (wv & 1) * WN;
  const int bxl = SWZ ? ((blockIdx.x & 7) * (gridDim.x >> 3) + (blockIdx.x >> 3))
                      : blockIdx.x;
  const int bm0 = blockIdx.y * TBM, bn0 = bxl * TBN;
  const int q = lane >> 4, r16 = lane & 15;
  const int srow = tid / TPR, scol = (tid % TPR) * 8;
  const int kc = K / KSPLIT;
  const int k0 = (KSPLIT > 1) ? blockIdx.z * kc : 0;
  const int kend = k0 + kc;

  f32x4 acc[MI][NJ];
#pragma unroll
  for (int i = 0; i < MI; i++)
#pragma unroll
    for (int j = 0; j < NJ; j++)
#pragma unroll
      for (int r = 0; r < 4; r++) acc[i][j][r] = 0.f;

  const u16* Ag = A + (size_t)bm0 * K + scol + k0;
  const u16* Wg = Wt + (size_t)bn0 * K + scol + k0;
  s16x8 ra[ALn], rb[BLn];
#pragma unroll
  for (int i = 0; i < ALn; i++) ra[i] = *(const s16x8*)(Ag + (size_t)(srow + i * RPP) * K);
#pragma unroll
  for (int i = 0; i < BLn; i++) rb[i] = *(const s16x8*)(Wg + (size_t)(srow + i * RPP) * K);

  for (int kt = k0; kt < kend; kt += BK) {
    __syncthreads();
#pragma unroll
    for (int i = 0; i < ALn; i++) *(s16x8*)&sA[(srow + i * RPP) * LDT + scol] = ra[i];
#pragma unroll
    for (int i = 0; i < BLn; i++) *(s16x8*)&sB[(srow + i * RPP) * LDT + scol] = rb[i];
    __syncthreads();
    int kn = kt + BK - k0;
    if (kn < kc) {
#pragma unroll
      for (int i = 0; i < ALn; i++) ra[i] = *(const s16x8*)(Ag + (size_t)(srow + i * RPP) * K + kn);
#pragma unroll
      for (int i = 0; i < BLn; i++) rb[i] = *(const s16x8*)(Wg + (size_t)(srow + i * RPP) * K + kn);
    }
#pragma unroll
    for (int kk = 0; kk < KK; kk++) {
      s16x8 fa[MI], fb[NJ];
#pragma unroll
      for (int i = 0; i < MI; i++)
        fa[i] = *(const s16x8*)&sA[(wm + i * 16 + r16) * LDT + kk * 32 + q * 8];
#pragma unroll
      for (int j = 0; j < NJ; j++)
        fb[j] = *(const s16x8*)&sB[(wn + j * 16 + r16) * LDT + kk * 32 + q * 8];
#pragma unroll
      for (int i = 0; i < MI; i++)
#pragma unroll
        for (int j = 0; j < NJ; j++)
          acc[i][j] = __builtin_amdgcn_mfma_f32_16x16x32_bf16(fa[i], fb[j], acc[i][j], 0, 0, 0);
    }
  }
  OUT* Cz = C + ((KSPLIT > 1) ? (size_t)blockIdx.z * M * N : 0);
#pragma unroll
  for (int i = 0; i < MI; i++)
#pragma unroll
    for (int j = 0; j < NJ; j++) {
      int row0 = bm0 + wm + i * 16 + q * 4;
      int col = bn0 + wn + j * 16 + r16;
#pragma unroll
      for (int r = 0; r < 4; r++) {
        size_t off = (size_t)(row0 + r) * N + col;
        float v = acc[i][j][r];
        if constexpr (EPI == 1) v += X[off];
        if constexpr (sizeof(OUT) == 2) Cz[off] = f2bf(v);
        else                            Cz[off] = v;
      }
    }
}

// ---------------- depthwise causal conv (DC=4) + silu ----------------
__global__ __launch_bounds__(256) void conv_silu_kernel(const u16* __restrict__ xz,
    const float* __restrict__ cw, const float* __restrict__ cb, u16* __restrict__ xc) {
  int t = blockIdx.x;
  int l = t & (SEQ - 1);
  int c0 = threadIdx.x * 8;
  float acc[8], wk[8][4];
#pragma unroll
  for (int j = 0; j < 8; j++) {
    float4 wv = ((const float4*)cw)[c0 + j];
    wk[j][0] = wv.x; wk[j][1] = wv.y; wk[j][2] = wv.z; wk[j][3] = wv.w;
    acc[j] = cb[c0 + j];
  }
#pragma unroll
  for (int k = 0; k < 4; k++) {
    int lk = l - 3 + k;
    if (lk >= 0) {
      u16x8 v = *(const u16x8*)(xz + (size_t)(t - 3 + k) * (2 * DI_) + c0);
#pragma unroll
      for (int j = 0; j < 8; j++) acc[j] = fmaf(bf2f(v[j]), wk[j][k], acc[j]);
    }
  }
  u16x8 o;
#pragma unroll
  for (int j = 0; j < 8; j++) {
    float a = acc[j];
    o[j] = f2bf(a / (1.0f + __expf(-a)));
  }
  *(u16x8*)(xc + (size_t)t * DI_ + c0) = o;
}

// ============ cooperative fused scan ============
// 1024 blocks x 256 thr (4 blocks/CU co-resident).
// phase0: xp_finish (2 tokens/block). phase1: segment scan -> P,Q.
// phase2: serial prefix over 16 segments (65536 chains on blocks 0..255).
// phase3: resume from Hin, produce gated y.
__global__ __launch_bounds__(256, 4) void scan_fused(
    const float* __restrict__ part, const float* __restrict__ dtw,
    const float* __restrict__ dtb, u16* __restrict__ xz, float* __restrict__ bc,
    const u16* __restrict__ xc, const float* __restrict__ A_log,
    const float* __restrict__ Dskip, float* __restrict__ P, float* __restrict__ Q,
    u16* __restrict__ yb) {
  cg::grid_group grid = cg::this_grid();
  const int bid = blockIdx.x;
  const int tid = threadIdx.x;
  __shared__ float xps[64];

  // ---- phase 0: xp split-K reduce + delta + bc, tokens 2*bid, 2*bid+1 ----
  for (int tt = 0; tt < 2; tt++) {
    int t = bid * 2 + tt;
    if (tid < 64) {
      float s = 0.f;
#pragma unroll
      for (int k = 0; k < 8; k++)
        s += part[(size_t)k * NTOK * 64 + (size_t)t * 64 + tid];
      xps[tid] = s;
    }
    __syncthreads();
    if (tid < 32) bc[(size_t)t * 32 + tid] = xps[1 + tid];
    float dr = xps[0];
    int c0 = tid * 8;
    float wv8[8], bv8[8];
    *(float4*)wv8 = ((const float4*)(dtw + c0))[0];
    *(float4*)(wv8 + 4) = ((const float4*)(dtw + c0))[1];
    *(float4*)bv8 = ((const float4*)(dtb + c0))[0];
    *(float4*)(bv8 + 4) = ((const float4*)(dtb + c0))[1];
    u16x8 o;
#pragma unroll
    for (int j = 0; j < 8; j++) o[j] = f2bf(softplus_f(dr * wv8[j] + bv8[j]));
    *(u16x8*)(xz + (size_t)t * (2 * DI_) + c0) = o;
    __syncthreads();
  }
  grid.sync();

  // decode scan coordinates
  const int lane = tid & 63, wv = tid >> 6;
  const int nl = (lane & 3) * 4;
  const int d_blk = bid & 31, seg = (bid >> 5) & 15, b = bid >> 9;
  const int d = d_blk * 64 + wv * 16 + (lane >> 2);
  const int t0 = b * SEQ + seg * LSEG;
  float4 Ain = *(const float4*)(A_log + d * DS_ + nl);
  f32x4 Av;
  Av[0] = -__expf(Ain.x); Av[1] = -__expf(Ain.y);
  Av[2] = -__expf(Ain.z); Av[3] = -__expf(Ain.w);
  const size_t idx = ((size_t)((b * NSEG + seg) * DI_ + d)) * 16 + nl;

  // ---- phase 1: local segment scan (h_in = 0) ----
  {
    f32x4 Pv, h;
#pragma unroll
    for (int i = 0; i < 4; i++) { Pv[i] = 1.f; h[i] = 0.f; }
#pragma unroll 4
    for (int j = 0; j < LSEG; j++) {
      int t = t0 + j;
      float delta = bf2f(xz[(size_t)t * (2 * DI_) + d]);
      float xcv = bf2f(xc[(size_t)t * DI_ + d]);
      float4 B4 = *(const float4*)(bc + (size_t)t * 32 + nl);
      float du = delta * xcv;
#pragma unroll
      for (int i = 0; i < 4; i++) {
        float a = __expf(delta * Av[i]);
        Pv[i] *= a;
        float bi = (i == 0) ? B4.x : (i == 1) ? B4.y : (i == 2) ? B4.z : B4.w;
        h[i] = fmaf(a, h[i], du * bi);
      }
    }
    *(f32x4*)(P + idx) = Pv;
    *(f32x4*)(Q + idx) = h;
  }
  grid.sync();

  // ---- phase 2: exclusive prefix over segments (in-place on Q) ----
  {
    int g = bid * 256 + tid;
    if (g < BATCH * DI_ * 16) {
      int n2 = g & 15, d2 = (g >> 4) & (DI_ - 1), b2 = g >> 15;
      size_t base = ((size_t)b2 * NSEG * DI_ + d2) * 16 + n2;
      constexpr size_t STR = (size_t)DI_ * 16;
      float p_[NSEG], q_[NSEG];
#pragma unroll
      for (int s = 0; s < NSEG; s++) {
        p_[s] = P[base + s * STR];
        q_[s] = Q[base + s * STR];
      }
      float hh = 0.f;
#pragma unroll
      for (int s = 0; s < NSEG; s++) {
        Q[base + s * STR] = hh;
        hh = fmaf(p_[s], hh, q_[s]);
      }
    }
  }
  grid.sync();

  // ---- phase 3: resume from Hin, fused gate ----
  {
    float Dv = Dskip[d];
    f32x4 h = *(const f32x4*)(Q + idx);
#pragma unroll 4
    for (int j = 0; j < LSEG; j++) {
      int t = t0 + j;
      float delta = bf2f(xz[(size_t)t * (2 * DI_) + d]);
      float xcv = bf2f(xc[(size_t)t * DI_ + d]);
      float4 B4 = *(const float4*)(bc + (size_t)t * 32 + nl);
      float4 C4 = *(const float4*)(bc + (size_t)t * 32 + 16 + nl);
      float du = delta * xcv;
#pragma unroll
      for (int i = 0; i < 4; i++) {
        float a = __expf(delta * Av[i]);
        float bi = (i == 0) ? B4.x : (i == 1) ? B4.y : (i == 2) ? B4.z : B4.w;
        h[i] = fmaf(a, h[i], du * bi);
      }
      float p = h[0] * C4.x;
      p = fmaf(h[1], C4.y, p);
      p = fmaf(h[2], C4.z, p);
      p = fmaf(h[3], C4.w, p);
      p += __shfl_xor(p, 1);
      p += __shfl_xor(p, 2);
      if ((lane & 3) == 0) {
        float z = bf2f(xz[(size_t)t * (2 * DI_) + DI_ + d]);
        float sz = z / (1.0f + __expf(-z));
        yb[(size_t)t * DI_ + d] = f2bf((p + xcv * Dv) * sz);
      }
    }
  }
}

extern "C" void kernel_launch(void* const* d_in, const int* in_sizes, int n_in,
                              void* d_out, int out_size, void* d_ws, size_t ws_size,
                              hipStream_t stream) {
  const float* x      = (const float*)d_in[0];
  const float* norm_w = (const float*)d_in[1];
  const float* norm_b = (const float*)d_in[2];
  const float* in_w   = (const float*)d_in[3];
  const float* conv_w = (const float*)d_in[4];
  const float* conv_b = (const float*)d_in[5];
  const float* xproj_w= (const float*)d_in[6];
  const float* dt_w   = (const float*)d_in[7];
  const float* dt_b   = (const float*)d_in[8];
  const float* A_log  = (const float*)d_in[9];
  const float* D_skip = (const float*)d_in[10];
  const float* out_w  = (const float*)d_in[11];
  float* out = (float*)d_out;

  char* ws = (char*)d_ws;
  size_t off = 0;
  auto alloc = [&](size_t bytes) { void* p = ws + off; off += (bytes + 255) & ~255ULL; return p; };
  u16* in_w_bf  = (u16*)alloc((size_t)2 * DI_ * DIM_ * 2);
  u16* out_w_bf = (u16*)alloc((size_t)DIM_ * DI_ * 2);
  u16* xpw_bf   = (u16*)alloc((size_t)64 * DI_ * 2);
  u16* xn       = (u16*)alloc((size_t)NTOK * DIM_ * 2);
  u16* xz       = (u16*)alloc((size_t)NTOK * 2 * DI_ * 2);
  u16* xc       = (u16*)alloc((size_t)NTOK * DI_ * 2);
  float* bc     = (float*)alloc((size_t)NTOK * 32 * 4);
  float* xp_part= (float*)alloc((size_t)8 * NTOK * 64 * 4);
  float* P      = (float*)alloc((size_t)BATCH * NSEG * DI_ * 16 * 4);  // 4.19 MB
  float* Q      = (float*)alloc((size_t)BATCH * NSEG * DI_ * 16 * 4);  // 4.19 MB
  u16* yb       = (u16*)alloc((size_t)NTOK * DI_ * 2);

  // 1: weight conversions + LN, one node
  cvt_ln_kernel<<<CVT_BLOCKS + NTOK, 256, 0, stream>>>(in_w, out_w, xproj_w, x,
                                                       norm_w, norm_b, in_w_bf,
                                                       out_w_bf, xpw_bf, xn);
  // 2: in_proj 128x128, BK=64, XCD-swizzled -> 512 blocks
  gemm_bt<128, 128, 64, u16, 0, 1, 1><<<dim3((2 * DI_) / 128, NTOK / 128), 256, 0, stream>>>(
      xn, in_w_bf, xz, nullptr, NTOK, 2 * DI_, DIM_);
  // 3
  conv_silu_kernel<<<NTOK, 256, 0, stream>>>(xz, conv_w, conv_b, xc);
  // 4: x_proj split-K=8, BK=32 -> 256 blocks
  gemm_bt<64, 64, 32, float, 0, 8><<<dim3(1, NTOK / 64, 8), 256, 0, stream>>>(
      xc, xpw_bf, xp_part, nullptr, NTOK, 64, DI_);
  // 5: cooperative fused scan (xp_finish + pass1 + combine + pass2+gate)
  {
    void* args[] = {(void*)&xp_part, (void*)&dt_w, (void*)&dt_b, (void*)&xz,
                    (void*)&bc, (void*)&xc, (void*)&A_log, (void*)&D_skip,
                    (void*)&P, (void*)&Q, (void*)&yb};
    hipLaunchCooperativeKernel((const void*)scan_fused, dim3(1024), dim3(256),
                               args, 0, stream);
  }
  // 6: out_proj 64x64, BK=64, EPI=1, XCD-swizzled -> 512 blocks
  gemm_bt<64, 64, 64, float, 1, 1, 1><<<dim3(DIM_ / 64, NTOK / 64), 256, 0, stream>>>(
      yb, out_w_bf, out, x, NTOK, DIM_, DI_);
}

// Round 13
// 233.047 us; speedup vs baseline: 2.3627x; 2.3627x over previous
//
#include <hip/hip_runtime.h>
#include <stdint.h>

#define BATCH 2
#define SEQ   1024
#define DIM_  1024
#define DS_   16
#define DI_   2048
#define NTOK  (BATCH*SEQ)   // 2048
#define NSEG  32
#define LSEG  (SEQ/NSEG)    // 32

typedef unsigned short u16;
using s16x8 = __attribute__((ext_vector_type(8))) short;
using f32x4 = __attribute__((ext_vector_type(4))) float;
using u16x4 = __attribute__((ext_vector_type(4))) unsigned short;
using u16x8 = __attribute__((ext_vector_type(8))) unsigned short;

__device__ __forceinline__ float bf2f(u16 u) {
  union { unsigned int i; float f; } c; c.i = ((unsigned int)u) << 16; return c.f;
}
__device__ __forceinline__ u16 f2bf(float f) {
  union { float f; unsigned int i; } c; c.f = f;
  unsigned int r = c.i + 0x7fffu + ((c.i >> 16) & 1u);
  return (u16)(r >> 16);
}
__device__ __forceinline__ float softplus_f(float x) {
  return (x > 15.f) ? x : __logf(1.f + __expf(x));
}
__device__ __forceinline__ u16x4 f4_to_bf(float4 v) {
  u16x4 r; r[0] = f2bf(v.x); r[1] = f2bf(v.y); r[2] = f2bf(v.z); r[3] = f2bf(v.w);
  return r;
}

// ---------------- merged: weight conversions + LayerNorm ----------------
#define N4_INW  (2 * DI_ * DIM_ / 4)   // 1048576
#define N4_OUTW (DIM_ * DI_ / 4)       // 524288
#define CVT_BLOCKS ((N4_INW + N4_OUTW + 32768) / 256)   // 6272
__global__ __launch_bounds__(256) void cvt_ln_kernel(const float* __restrict__ in_w,
    const float* __restrict__ out_w, const float* __restrict__ xproj_w,
    const float* __restrict__ x, const float* __restrict__ nw,
    const float* __restrict__ nb, u16* __restrict__ in_w_bf,
    u16* __restrict__ out_w_bf, u16* __restrict__ xpw_bf, u16* __restrict__ xn) {
  int tid = threadIdx.x;
  if (blockIdx.x < CVT_BLOCKS) {
    int i = blockIdx.x * 256 + tid;
    if (i < N4_INW) {
      ((u16x4*)in_w_bf)[i] = f4_to_bf(((const float4*)in_w)[i]);
    } else if (i < N4_INW + N4_OUTW) {
      int j = i - N4_INW;
      ((u16x4*)out_w_bf)[j] = f4_to_bf(((const float4*)out_w)[j]);
    } else {
      int j = i - (N4_INW + N4_OUTW);
      if (j >= 32768) return;
      int p = (j * 4) >> 11;
      u16x4 r;
      if (p < 33) r = f4_to_bf(((const float4*)xproj_w)[j]);
      else { r[0] = 0; r[1] = 0; r[2] = 0; r[3] = 0; }
      ((u16x4*)xpw_bf)[j] = r;
    }
    return;
  }
  // LayerNorm branch
  int t = blockIdx.x - CVT_BLOCKS;
  const float* row = x + (size_t)t * DIM_;
  float4 v = ((const float4*)row)[tid];
  float f[4] = {v.x, v.y, v.z, v.w};
  float s = 0.f, sq = 0.f;
#pragma unroll
  for (int j = 0; j < 4; j++) { s += f[j]; sq += f[j] * f[j]; }
#pragma unroll
  for (int m = 1; m < 64; m <<= 1) { s += __shfl_xor(s, m); sq += __shfl_xor(sq, m); }
  __shared__ float rs_[4], rq_[4];
  int wv = tid >> 6;
  if ((tid & 63) == 0) { rs_[wv] = s; rq_[wv] = sq; }
  __syncthreads();
  s = rs_[0] + rs_[1] + rs_[2] + rs_[3];
  sq = rq_[0] + rq_[1] + rq_[2] + rq_[3];
  float mu = s * (1.0f / DIM_);
  float var = sq * (1.0f / DIM_) - mu * mu;
  float rstd = rsqrtf(var + 1e-5f);
  float4 wn = ((const float4*)nw)[tid];
  float4 bn = ((const float4*)nb)[tid];
  u16x4 o;
  o[0] = f2bf((f[0] - mu) * rstd * wn.x + bn.x);
  o[1] = f2bf((f[1] - mu) * rstd * wn.y + bn.y);
  o[2] = f2bf((f[2] - mu) * rstd * wn.z + bn.z);
  o[3] = f2bf((f[3] - mu) * rstd * wn.w + bn.w);
  *(u16x4*)(xn + (size_t)t * DIM_ + tid * 4) = o;
}

// ---------------- GEMM C = A(M,K)bf16 * W(N,K)^T bf16, f32 acc ----------------
template<int TBM, int TBN, int BK, typename OUT, int EPI, int KSPLIT = 1, int SWZ = 0>
__global__ __launch_bounds__(256) void gemm_bt(const u16* __restrict__ A,
    const u16* __restrict__ Wt, OUT* __restrict__ C, const float* __restrict__ X,
    int M, int N, int K) {
  constexpr int LDT = BK + 8;
  constexpr int TPR = BK / 8;
  constexpr int RPP = 256 / TPR;
  constexpr int ALn = TBM / RPP;
  constexpr int BLn = TBN / RPP;
  constexpr int KK = BK / 32;
  constexpr int WM = TBM / 2, WN = TBN / 2;
  constexpr int MI = WM / 16, NJ = WN / 16;
  __shared__ __align__(16) u16 sA[TBM * LDT];
  __shared__ __align__(16) u16 sB[TBN * LDT];
  const int tid = threadIdx.x;
  const int lane = tid & 63, wv = tid >> 6;
  const int wm = (wv >> 1) * WM, wn = (wv & 1) * WN;
  const int bxl = SWZ ? ((blockIdx.x & 7) * (gridDim.x >> 3) + (blockIdx.x >> 3))
                      : blockIdx.x;
  const int bm0 = blockIdx.y * TBM, bn0 = bxl * TBN;
  const int q = lane >> 4, r16 = lane & 15;
  const int srow = tid / TPR, scol = (tid % TPR) * 8;
  const int kc = K / KSPLIT;
  const int k0 = (KSPLIT > 1) ? blockIdx.z * kc : 0;
  const int kend = k0 + kc;

  f32x4 acc[MI][NJ];
#pragma unroll
  for (int i = 0; i < MI; i++)
#pragma unroll
    for (int j = 0; j < NJ; j++)
#pragma unroll
      for (int r = 0; r < 4; r++) acc[i][j][r] = 0.f;

  const u16* Ag = A + (size_t)bm0 * K + scol + k0;
  const u16* Wg = Wt + (size_t)bn0 * K + scol + k0;
  s16x8 ra[ALn], rb[BLn];
#pragma unroll
  for (int i = 0; i < ALn; i++) ra[i] = *(const s16x8*)(Ag + (size_t)(srow + i * RPP) * K);
#pragma unroll
  for (int i = 0; i < BLn; i++) rb[i] = *(const s16x8*)(Wg + (size_t)(srow + i * RPP) * K);

  for (int kt = k0; kt < kend; kt += BK) {
    __syncthreads();
#pragma unroll
    for (int i = 0; i < ALn; i++) *(s16x8*)&sA[(srow + i * RPP) * LDT + scol] = ra[i];
#pragma unroll
    for (int i = 0; i < BLn; i++) *(s16x8*)&sB[(srow + i * RPP) * LDT + scol] = rb[i];
    __syncthreads();
    int kn = kt + BK - k0;
    if (kn < kc) {
#pragma unroll
      for (int i = 0; i < ALn; i++) ra[i] = *(const s16x8*)(Ag + (size_t)(srow + i * RPP) * K + kn);
#pragma unroll
      for (int i = 0; i < BLn; i++) rb[i] = *(const s16x8*)(Wg + (size_t)(srow + i * RPP) * K + kn);
    }
#pragma unroll
    for (int kk = 0; kk < KK; kk++) {
      s16x8 fa[MI], fb[NJ];
#pragma unroll
      for (int i = 0; i < MI; i++)
        fa[i] = *(const s16x8*)&sA[(wm + i * 16 + r16) * LDT + kk * 32 + q * 8];
#pragma unroll
      for (int j = 0; j < NJ; j++)
        fb[j] = *(const s16x8*)&sB[(wn + j * 16 + r16) * LDT + kk * 32 + q * 8];
#pragma unroll
      for (int i = 0; i < MI; i++)
#pragma unroll
        for (int j = 0; j < NJ; j++)
          acc[i][j] = __builtin_amdgcn_mfma_f32_16x16x32_bf16(fa[i], fb[j], acc[i][j], 0, 0, 0);
    }
  }
  OUT* Cz = C + ((KSPLIT > 1) ? (size_t)blockIdx.z * M * N : 0);
#pragma unroll
  for (int i = 0; i < MI; i++)
#pragma unroll
    for (int j = 0; j < NJ; j++) {
      int row0 = bm0 + wm + i * 16 + q * 4;
      int col = bn0 + wn + j * 16 + r16;
#pragma unroll
      for (int r = 0; r < 4; r++) {
        size_t off = (size_t)(row0 + r) * N + col;
        float v = acc[i][j][r];
        if constexpr (EPI == 1) v += X[off];
        if constexpr (sizeof(OUT) == 2) Cz[off] = f2bf(v);
        else                            Cz[off] = v;
      }
    }
}

// ---------------- depthwise causal conv (DC=4) + silu ----------------
__global__ __launch_bounds__(256) void conv_silu_kernel(const u16* __restrict__ xz,
    const float* __restrict__ cw, const float* __restrict__ cb, u16* __restrict__ xc) {
  int t = blockIdx.x;
  int l = t & (SEQ - 1);
  int c0 = threadIdx.x * 8;
  float acc[8], wk[8][4];
#pragma unroll
  for (int j = 0; j < 8; j++) {
    float4 wv = ((const float4*)cw)[c0 + j];
    wk[j][0] = wv.x; wk[j][1] = wv.y; wk[j][2] = wv.z; wk[j][3] = wv.w;
    acc[j] = cb[c0 + j];
  }
#pragma unroll
  for (int k = 0; k < 4; k++) {
    int lk = l - 3 + k;
    if (lk >= 0) {
      u16x8 v = *(const u16x8*)(xz + (size_t)(t - 3 + k) * (2 * DI_) + c0);
#pragma unroll
      for (int j = 0; j < 8; j++) acc[j] = fmaf(bf2f(v[j]), wk[j][k], acc[j]);
    }
  }
  u16x8 o;
#pragma unroll
  for (int j = 0; j < 8; j++) {
    float a = acc[j];
    o[j] = f2bf(a / (1.0f + __expf(-a)));
  }
  *(u16x8*)(xc + (size_t)t * DI_ + c0) = o;
}

// ---------------- fused: split-K reduce of xproj + delta(softplus) + B/C repack ----------------
__global__ __launch_bounds__(256) void xp_finish_kernel(const float* __restrict__ part,
    const float* __restrict__ dtw, const float* __restrict__ dtb,
    u16* __restrict__ xz, float* __restrict__ bc) {
  int t = blockIdx.x;
  int tid = threadIdx.x;
  __shared__ float xps[64];
  if (tid < 64) {
    float s = 0.f;
#pragma unroll
    for (int k = 0; k < 8; k++)
      s += part[(size_t)k * NTOK * 64 + (size_t)t * 64 + tid];
    xps[tid] = s;
  }
  __syncthreads();
  if (tid < 32) bc[(size_t)t * 32 + tid] = xps[1 + tid];
  float dr = xps[0];
  int c0 = tid * 8;
  float wv[8], bv[8];
  *(float4*)wv = ((const float4*)(dtw + c0))[0];
  *(float4*)(wv + 4) = ((const float4*)(dtw + c0))[1];
  *(float4*)bv = ((const float4*)(dtb + c0))[0];
  *(float4*)(bv + 4) = ((const float4*)(dtb + c0))[1];
  u16x8 o;
#pragma unroll
  for (int j = 0; j < 8; j++) o[j] = f2bf(softplus_f(dr * wv[j] + bv[j]));
  *(u16x8*)(xz + (size_t)t * (2 * DI_) + c0) = o;
}

// ============ segmented selective scan (4 states/lane) ============
__global__ __launch_bounds__(256) void scan_pass1(const float* __restrict__ bc,
    const u16* __restrict__ dlt, const u16* __restrict__ xc,
    const float* __restrict__ A_log, float* __restrict__ P, float* __restrict__ Q) {
  int tid = threadIdx.x;
  int lane = tid & 63, wv = tid >> 6;
  int nl = (lane & 3) * 4;
  int d = blockIdx.x * 64 + wv * 16 + (lane >> 2);
  int s = blockIdx.y, b = blockIdx.z;
  int t0 = b * SEQ + s * LSEG;
  float4 Ain = *(const float4*)(A_log + d * DS_ + nl);
  f32x4 Av;
  Av[0] = -__expf(Ain.x); Av[1] = -__expf(Ain.y);
  Av[2] = -__expf(Ain.z); Av[3] = -__expf(Ain.w);
  f32x4 Pv, h;
#pragma unroll
  for (int i = 0; i < 4; i++) { Pv[i] = 1.f; h[i] = 0.f; }
#pragma unroll 8
  for (int j = 0; j < LSEG; j++) {
    int t = t0 + j;
    float delta = bf2f(dlt[(size_t)t * (2 * DI_) + d]);
    float xcv = bf2f(xc[(size_t)t * DI_ + d]);
    float4 B4 = *(const float4*)(bc + (size_t)t * 32 + nl);
    float du = delta * xcv;
#pragma unroll
    for (int i = 0; i < 4; i++) {
      float a = __expf(delta * Av[i]);
      Pv[i] *= a;
      float bi = (i == 0) ? B4.x : (i == 1) ? B4.y : (i == 2) ? B4.z : B4.w;
      h[i] = fmaf(a, h[i], du * bi);
    }
  }
  size_t idx = ((size_t)((b * NSEG + s) * DI_ + d)) * 16 + nl;
  *(f32x4*)(P + idx) = Pv;
  *(f32x4*)(Q + idx) = h;
}

__global__ __launch_bounds__(256) void scan_combine(const float* __restrict__ P,
    float* __restrict__ Q) {
  int g = blockIdx.x * 256 + threadIdx.x;
  int n = g & 15, d = (g >> 4) & (DI_ - 1), b = g >> 15;
  size_t base = ((size_t)b * NSEG * DI_ + d) * 16 + n;
  constexpr size_t STR = (size_t)DI_ * 16;
  float p_[NSEG], q_[NSEG];
#pragma unroll
  for (int s = 0; s < NSEG; s++) {
    p_[s] = P[base + s * STR];
    q_[s] = Q[base + s * STR];
  }
  float hh = 0.f;
#pragma unroll
  for (int s = 0; s < NSEG; s++) {
    Q[base + s * STR] = hh;
    hh = fmaf(p_[s], hh, q_[s]);
  }
}

// pass2 + fused gate: y = (p + xc*D) * silu(z)
__global__ __launch_bounds__(256) void scan_pass2(const float* __restrict__ bc,
    const u16* __restrict__ dlt, const u16* __restrict__ xc,
    const float* __restrict__ A_log, const float* __restrict__ Dskip,
    const float* __restrict__ Hin, u16* __restrict__ yb) {
  int tid = threadIdx.x;
  int lane = tid & 63, wv = tid >> 6;
  int nl = (lane & 3) * 4;
  int d = blockIdx.x * 64 + wv * 16 + (lane >> 2);
  int s = blockIdx.y, b = blockIdx.z;
  int t0 = b * SEQ + s * LSEG;
  float4 Ain = *(const float4*)(A_log + d * DS_ + nl);
  f32x4 Av;
  Av[0] = -__expf(Ain.x); Av[1] = -__expf(Ain.y);
  Av[2] = -__expf(Ain.z); Av[3] = -__expf(Ain.w);
  float Dv = Dskip[d];
  size_t idx = ((size_t)((b * NSEG + s) * DI_ + d)) * 16 + nl;
  f32x4 h = *(const f32x4*)(Hin + idx);
#pragma unroll 8
  for (int j = 0; j < LSEG; j++) {
    int t = t0 + j;
    float delta = bf2f(dlt[(size_t)t * (2 * DI_) + d]);
    float xcv = bf2f(xc[(size_t)t * DI_ + d]);
    float4 B4 = *(const float4*)(bc + (size_t)t * 32 + nl);
    float4 C4 = *(const float4*)(bc + (size_t)t * 32 + 16 + nl);
    float du = delta * xcv;
#pragma unroll
    for (int i = 0; i < 4; i++) {
      float a = __expf(delta * Av[i]);
      float bi = (i == 0) ? B4.x : (i == 1) ? B4.y : (i == 2) ? B4.z : B4.w;
      h[i] = fmaf(a, h[i], du * bi);
    }
    float p = h[0] * C4.x;
    p = fmaf(h[1], C4.y, p);
    p = fmaf(h[2], C4.z, p);
    p = fmaf(h[3], C4.w, p);
    p += __shfl_xor(p, 1);
    p += __shfl_xor(p, 2);
    if ((lane & 3) == 0) {
      float z = bf2f(dlt[(size_t)t * (2 * DI_) + DI_ + d]);
      float sz = z / (1.0f + __expf(-z));
      yb[(size_t)t * DI_ + d] = f2bf((p + xcv * Dv) * sz);
    }
  }
}

extern "C" void kernel_launch(void* const* d_in, const int* in_sizes, int n_in,
                              void* d_out, int out_size, void* d_ws, size_t ws_size,
                              hipStream_t stream) {
  const float* x      = (const float*)d_in[0];
  const float* norm_w = (const float*)d_in[1];
  const float* norm_b = (const float*)d_in[2];
  const float* in_w   = (const float*)d_in[3];
  const float* conv_w = (const float*)d_in[4];
  const float* conv_b = (const float*)d_in[5];
  const float* xproj_w= (const float*)d_in[6];
  const float* dt_w   = (const float*)d_in[7];
  const float* dt_b   = (const float*)d_in[8];
  const float* A_log  = (const float*)d_in[9];
  const float* D_skip = (const float*)d_in[10];
  const float* out_w  = (const float*)d_in[11];
  float* out = (float*)d_out;

  char* ws = (char*)d_ws;
  size_t off = 0;
  auto alloc = [&](size_t bytes) { void* p = ws + off; off += (bytes + 255) & ~255ULL; return p; };
  u16* in_w_bf  = (u16*)alloc((size_t)2 * DI_ * DIM_ * 2);
  u16* out_w_bf = (u16*)alloc((size_t)DIM_ * DI_ * 2);
  u16* xpw_bf   = (u16*)alloc((size_t)64 * DI_ * 2);
  u16* xn       = (u16*)alloc((size_t)NTOK * DIM_ * 2);
  u16* xz       = (u16*)alloc((size_t)NTOK * 2 * DI_ * 2);
  u16* xc       = (u16*)alloc((size_t)NTOK * DI_ * 2);
  float* bc     = (float*)alloc((size_t)NTOK * 32 * 4);
  float* xp_part= (float*)alloc((size_t)8 * NTOK * 64 * 4);
  float* P      = (float*)alloc((size_t)BATCH * NSEG * DI_ * 16 * 4);
  float* Q      = (float*)alloc((size_t)BATCH * NSEG * DI_ * 16 * 4);
  u16* yb       = (u16*)alloc((size_t)NTOK * DI_ * 2);

  // 1: weight conversions + LN, one node
  cvt_ln_kernel<<<CVT_BLOCKS + NTOK, 256, 0, stream>>>(in_w, out_w, xproj_w, x,
                                                       norm_w, norm_b, in_w_bf,
                                                       out_w_bf, xpw_bf, xn);
  // 2: in_proj 128x128, BK=64, XCD-swizzled -> 512 blocks
  gemm_bt<128, 128, 64, u16, 0, 1, 1><<<dim3((2 * DI_) / 128, NTOK / 128), 256, 0, stream>>>(
      xn, in_w_bf, xz, nullptr, NTOK, 2 * DI_, DIM_);
  // 3
  conv_silu_kernel<<<NTOK, 256, 0, stream>>>(xz, conv_w, conv_b, xc);
  // 4: x_proj split-K=8, BK=32 -> 256 blocks
  gemm_bt<64, 64, 32, float, 0, 8><<<dim3(1, NTOK / 64, 8), 256, 0, stream>>>(
      xc, xpw_bf, xp_part, nullptr, NTOK, 64, DI_);
  // 5
  xp_finish_kernel<<<NTOK, 256, 0, stream>>>(xp_part, dt_w, dt_b, xz, bc);
  // 6
  scan_pass1<<<dim3(DI_ / 64, NSEG, BATCH), 256, 0, stream>>>(bc, xz, xc, A_log, P, Q);
  // 7
  scan_combine<<<BATCH * DI_ * 16 / 256, 256, 0, stream>>>(P, Q);
  // 8
  scan_pass2<<<dim3(DI_ / 64, NSEG, BATCH), 256, 0, stream>>>(bc, xz, xc, A_log, D_skip,
                                                              Q, yb);
  // 9: out_proj 64x64, BK=64, EPI=1, XCD-swizzled -> 512 blocks
  gemm_bt<64, 64, 64, float, 1, 1, 1><<<dim3(DIM_ / 64, NTOK / 64), 256, 0, stream>>>(
      yb, out_w_bf, out, x, NTOK, DIM_, DI_);
}